// Round 1
// baseline (83.682 us; speedup 1.0000x reference)
//
#include <hip/hip_runtime.h>
#include <hip/hip_bf16.h>
#include <stdint.h>

// Head: q=x@Wq, k=x@Wk, v=x@Wv ; wei=softmax(causal(q k^T / 8)) ; out=wei@v
// B=256, T=256, C=768, H=64. All MFMA in bf16 (threshold permits), accum fp32.

typedef __attribute__((ext_vector_type(8))) short short8;
typedef __attribute__((ext_vector_type(4))) short short4v;
typedef __attribute__((ext_vector_type(4))) float f32x4;

static __device__ __forceinline__ unsigned short f2bf(float f) {
  union { float f; uint32_t u; } v; v.f = f;
  uint32_t r = (v.u + 0x7FFFu + ((v.u >> 16) & 1u)) >> 16;  // RNE
  return (unsigned short)r;
}

// ---------------------------------------------------------------- prep: W -> Wt bf16 [192][768]
__global__ void wt_prep(const float* __restrict__ Wq, const float* __restrict__ Wk,
                        const float* __restrict__ Wv, unsigned short* __restrict__ Wt) {
  int idx = blockIdx.x * 256 + threadIdx.x;        // 0 .. 192*768-1
  if (idx >= 192 * 768) return;
  int row = idx / 768;                             // out col (m*64+c)
  int k = idx - row * 768;
  int m = row >> 6, c = row & 63;
  const float* W = (m == 0) ? Wq : (m == 1 ? Wk : Wv);
  Wt[idx] = f2bf(W[k * 64 + c]);
}

// ---------------------------------------------------------------- QKV projection
// block: 64 rows of x ; 4 waves, wave w owns rows [w*16, w*16+16), all 192 out cols.
__global__ __launch_bounds__(256) void qkv_kernel(
    const float* __restrict__ x, const unsigned short* __restrict__ Wt,
    unsigned short* __restrict__ Q, unsigned short* __restrict__ Kb,
    unsigned short* __restrict__ Vt) {
  __shared__ short xs[64 * 40];     // [64][32] bf16, stride 40 (pad 8 -> 2-way max)
  __shared__ short wsm[192 * 40];   // [192][32] bf16, stride 40
  const int tid = threadIdx.x;
  const int w = tid >> 6, lane = tid & 63;
  const int l15 = lane & 15, g = lane >> 4;
  const int row0 = blockIdx.x * 64;

  f32x4 acc[12];
  #pragma unroll
  for (int i = 0; i < 12; ++i) acc[i] = f32x4{0.f, 0.f, 0.f, 0.f};

  const int xr = tid >> 2;          // staging: row 0..63
  const int xc = (tid & 3) * 8;     // col 0,8,16,24

  for (int kk = 0; kk < 768; kk += 32) {
    // stage x tile [64][32] fp32 -> bf16
    {
      const float* src = x + (size_t)(row0 + xr) * 768 + kk + xc;
      float4 f0 = *reinterpret_cast<const float4*>(src);
      float4 f1 = *reinterpret_cast<const float4*>(src + 4);
      short8 v;
      v[0] = f2bf(f0.x); v[1] = f2bf(f0.y); v[2] = f2bf(f0.z); v[3] = f2bf(f0.w);
      v[4] = f2bf(f1.x); v[5] = f2bf(f1.y); v[6] = f2bf(f1.z); v[7] = f2bf(f1.w);
      *reinterpret_cast<short8*>(&xs[xr * 40 + xc]) = v;
    }
    // stage Wt tile [192][32] (bf16 from global, L2-resident)
    if (tid < 192) {
      const short8* src = reinterpret_cast<const short8*>(Wt + (size_t)tid * 768 + kk);
      short8* dst = reinterpret_cast<short8*>(&wsm[tid * 40]);
      dst[0] = src[0]; dst[1] = src[1]; dst[2] = src[2]; dst[3] = src[3];
    }
    __syncthreads();
    // A frag: row = w*16 + l15, k = g*8..+8
    short8 a = *reinterpret_cast<const short8*>(&xs[(w * 16 + l15) * 40 + g * 8]);
    #pragma unroll
    for (int ct = 0; ct < 12; ++ct) {
      short8 b = *reinterpret_cast<const short8*>(&wsm[(ct * 16 + l15) * 40 + g * 8]);
      acc[ct] = __builtin_amdgcn_mfma_f32_16x16x32_bf16(a, b, acc[ct], 0, 0, 0);
    }
    __syncthreads();
  }

  // epilogue: D layout col=l15, row=g*4+reg
  #pragma unroll
  for (int r = 0; r < 4; ++r) {
    int grow = row0 + w * 16 + g * 4 + r;
    size_t base = (size_t)grow * 64 + l15;
    #pragma unroll
    for (int ct = 0; ct < 4; ++ct) Q[base + ct * 16] = f2bf(acc[ct][r]);
    #pragma unroll
    for (int ct = 0; ct < 4; ++ct) Kb[base + ct * 16] = f2bf(acc[4 + ct][r]);
  }
  // V transposed: Vt[b][h][t], 4 consecutive t per lane -> 8B store
  {
    int grow0 = row0 + w * 16 + g * 4;
    int b = grow0 >> 8, t0 = grow0 & 255;
    #pragma unroll
    for (int ct = 0; ct < 4; ++ct) {
      int h = ct * 16 + l15;
      short4v pk;
      pk[0] = (short)f2bf(acc[8 + ct][0]);
      pk[1] = (short)f2bf(acc[8 + ct][1]);
      pk[2] = (short)f2bf(acc[8 + ct][2]);
      pk[3] = (short)f2bf(acc[8 + ct][3]);
      *reinterpret_cast<short4v*>(&Vt[((size_t)b * 64 + h) * 256 + t0]) = pk;
    }
  }
}

// ---------------------------------------------------------------- attention
// block = (batch b, q-tile qt of 64 rows); 4 waves, wave w owns 16 q-rows.
// LDS 64KB: [0,32K) K (XOR-swizzled) -> reused for P per-wave ; [32K,64K) Vt swizzled.
__global__ __launch_bounds__(256) void attn_kernel(
    const unsigned short* __restrict__ Q, const unsigned short* __restrict__ Kb,
    const unsigned short* __restrict__ Vt, float* __restrict__ out) {
  extern __shared__ char smem[];
  const int tid = threadIdx.x;
  const int w = tid >> 6, lane = tid & 63;
  const int l15 = lane & 15, g = lane >> 4;
  const int b = blockIdx.x >> 2, qt = blockIdx.x & 3;

  // stage K[b] : 256 rows x 64 h, swizzle byte ^= (key&7)<<4
  {
    const short8* src = reinterpret_cast<const short8*>(Kb + ((size_t)b * 256 + tid) * 64);
    int rowoff = tid * 128, swz = (tid & 7) << 4;
    #pragma unroll
    for (int j = 0; j < 8; ++j)
      *reinterpret_cast<short8*>(smem + ((rowoff + j * 16) ^ swz)) = src[j];
  }
  // stage Vt[b] : 64 h x 256 t, swizzle byte ^= (h&7)<<4
  {
    int h = tid >> 2, c0 = (tid & 3) * 64;
    const short8* src = reinterpret_cast<const short8*>(Vt + (size_t)b * 16384 + h * 256 + c0);
    char* vb = smem + 32768;
    int off = h * 512 + c0 * 2, swz = (h & 7) << 4;
    #pragma unroll
    for (int j = 0; j < 8; ++j)
      *reinterpret_cast<short8*>(vb + ((off + j * 16) ^ swz)) = src[j];
  }
  // Q frags (from global, contiguous 16B)
  const int trow0 = qt * 64 + w * 16;
  short8 qf0, qf1;
  {
    const short8* qsrc = reinterpret_cast<const short8*>(
        Q + ((size_t)b * 256 + trow0 + l15) * 64 + g * 8);
    qf0 = qsrc[0];   // h = g*8 .. +8      (k-chunk 0..31)
    qf1 = qsrc[4];   // h = 32 + g*8 .. +8 (k-chunk 32..63)
  }
  __syncthreads();

  // S = Q K^T : 16 key-tiles, full row in registers
  f32x4 s[16];
  #pragma unroll
  for (int t = 0; t < 16; ++t) {
    f32x4 a = f32x4{0.f, 0.f, 0.f, 0.f};
    int key = t * 16 + l15;
    int swz = (key & 7) << 4;
    short8 b0 = *reinterpret_cast<const short8*>(smem + ((key * 128 + g * 16) ^ swz));
    short8 b1 = *reinterpret_cast<const short8*>(smem + ((key * 128 + 64 + g * 16) ^ swz));
    a = __builtin_amdgcn_mfma_f32_16x16x32_bf16(qf0, b0, a, 0, 0, 0);
    a = __builtin_amdgcn_mfma_f32_16x16x32_bf16(qf1, b1, a, 0, 0, 0);
    s[t] = a;
  }

  // mask + softmax per q-row (4 rows/lane; row = trow0 + g*4 + r, key = t*16 + l15)
  #pragma unroll
  for (int r = 0; r < 4; ++r) {
    int trow = trow0 + g * 4 + r;
    float mx = -1e30f;
    #pragma unroll
    for (int t = 0; t < 16; ++t) {
      int key = t * 16 + l15;
      float v = s[t][r] * 0.125f;
      v = (key <= trow) ? v : -1e30f;
      s[t][r] = v;
      mx = fmaxf(mx, v);
    }
    mx = fmaxf(mx, __shfl_xor(mx, 1));
    mx = fmaxf(mx, __shfl_xor(mx, 2));
    mx = fmaxf(mx, __shfl_xor(mx, 4));
    mx = fmaxf(mx, __shfl_xor(mx, 8));
    float sum = 0.f;
    #pragma unroll
    for (int t = 0; t < 16; ++t) {
      float p = __expf(s[t][r] - mx);
      s[t][r] = p;
      sum += p;
    }
    sum += __shfl_xor(sum, 1);
    sum += __shfl_xor(sum, 2);
    sum += __shfl_xor(sum, 4);
    sum += __shfl_xor(sum, 8);
    float inv = 1.0f / sum;
    #pragma unroll
    for (int t = 0; t < 16; ++t) s[t][r] *= inv;
  }
  __syncthreads();   // all waves done reading K region

  // write P (bf16, normalized) into wave's quarter of retired-K region
  {
    char* pbase = smem + w * 8192;
    #pragma unroll
    for (int r = 0; r < 4; ++r) {
      int lr = g * 4 + r;
      int rowoff = lr * 512, swz = (lr & 7) << 4;
      #pragma unroll
      for (int t = 0; t < 16; ++t) {
        int key = t * 16 + l15;
        *reinterpret_cast<unsigned short*>(pbase + ((rowoff + key * 2) ^ swz)) =
            f2bf(s[t][r]);
      }
    }
  }

  // O = P V  (wave reads only its own P region -> no barrier needed)
  f32x4 o[4];
  #pragma unroll
  for (int i = 0; i < 4; ++i) o[i] = f32x4{0.f, 0.f, 0.f, 0.f};
  {
    const char* pbase = smem + w * 8192;
    const char* vbase = smem + 32768;
    int prow = l15, pswz = (prow & 7) << 4;
    #pragma unroll
    for (int kc = 0; kc < 8; ++kc) {
      int k0 = kc * 32 + g * 8;
      short8 a = *reinterpret_cast<const short8*>(pbase + ((prow * 512 + k0 * 2) ^ pswz));
      #pragma unroll
      for (int ht = 0; ht < 4; ++ht) {
        int h = ht * 16 + l15;
        short8 bv = *reinterpret_cast<const short8*>(
            vbase + ((h * 512 + k0 * 2) ^ ((h & 7) << 4)));
        o[ht] = __builtin_amdgcn_mfma_f32_16x16x32_bf16(a, bv, o[ht], 0, 0, 0);
      }
    }
  }

  // write out fp32 [b][t][h]
  #pragma unroll
  for (int r = 0; r < 4; ++r) {
    int trow = trow0 + g * 4 + r;
    float* dst = out + ((size_t)b * 256 + trow) * 64 + l15;
    #pragma unroll
    for (int ht = 0; ht < 4; ++ht) dst[ht * 16] = o[ht][r];
  }
}

// ---------------------------------------------------------------- launch
extern "C" void kernel_launch(void* const* d_in, const int* in_sizes, int n_in,
                              void* d_out, int out_size, void* d_ws, size_t ws_size,
                              hipStream_t stream) {
  const float* x  = (const float*)d_in[0];
  const float* Wq = (const float*)d_in[1];
  const float* Wk = (const float*)d_in[2];
  const float* Wv = (const float*)d_in[3];
  char* ws = (char*)d_ws;
  unsigned short* Wt = (unsigned short*)ws;                              // 294912 B
  unsigned short* Q  = (unsigned short*)(ws + 294912);                   // 8 MB
  unsigned short* Kb = (unsigned short*)(ws + 294912 + 8388608);         // 8 MB
  unsigned short* Vt = (unsigned short*)(ws + 294912 + 2 * 8388608);     // 8 MB
  float* out = (float*)d_out;

  hipLaunchKernelGGL(wt_prep, dim3(576), dim3(256), 0, stream, Wq, Wk, Wv, Wt);
  hipLaunchKernelGGL(qkv_kernel, dim3(1024), dim3(256), 0, stream, x, Wt, Q, Kb, Vt);
  hipLaunchKernelGGL(attn_kernel, dim3(1024), dim3(256), 65536, stream, Q, Kb, Vt, out);
}

// Round 2
// 58.290 us; speedup vs baseline: 1.4356x; 1.4356x over previous
//
#include <hip/hip_runtime.h>
#include <hip/hip_bf16.h>
#include <stdint.h>

// Fused single-head causal attention: q=x@Wq, k=x@Wk, v=x@Wv,
// out = softmax(causal(q k^T/8)) @ v.  B=256, T=256, C=768, H=64.
// One block per batch (256 blocks = 1/CU), 512 threads (8 waves).
// Phase 1: stream x (fp32->bf16) + Wt through double-buffered LDS, MFMA into
//          96 VGPR accumulators per wave (32 rows x 192 cols).
// Phase 2: K/Vt/Q written to swizzled LDS from accumulators (no global round
//          trip), per-wave causal flash-style attention entirely in LDS/regs.

typedef __attribute__((ext_vector_type(8))) short short8;
typedef __attribute__((ext_vector_type(4))) short short4v;
typedef __attribute__((ext_vector_type(4))) float f32x4;

#define MFMA16(a, b, c) __builtin_amdgcn_mfma_f32_16x16x32_bf16(a, b, c, 0, 0, 0)

static __device__ __forceinline__ unsigned short f2bf(float f) {
  union { float f; uint32_t u; } v; v.f = f;
  return (unsigned short)((v.u + 0x7FFFu + ((v.u >> 16) & 1u)) >> 16);  // RNE
}

// ---------------------------------------------------------------- prep: W -> Wt bf16 [192][768]
__global__ void wt_prep(const float* __restrict__ Wq, const float* __restrict__ Wk,
                        const float* __restrict__ Wv, unsigned short* __restrict__ Wt) {
  int idx = blockIdx.x * 256 + threadIdx.x;  // 0 .. 192*768-1
  if (idx >= 192 * 768) return;
  int row = idx / 768;  // out col (m*64+c)
  int k = idx - row * 768;
  int m = row >> 6, c = row & 63;
  const float* W = (m == 0) ? Wq : (m == 1 ? Wk : Wv);
  Wt[idx] = f2bf(W[k * 64 + c]);
}

// LDS layout (bytes):
//  [0,20480)       xs buf0 [256 rows][40 shorts]   (32 cols data + 8 pad)
//  [20480,40960)   xs buf1
//  [40960,56320)   ws buf0 [192 rows][40 shorts]
//  [56320,71680)   ws buf1
//  [71680,104448)  K  [256 keys][64 h]  stride 128B, swz ^((key&7)<<4)
//  [104448,137216) Vt [64 h][256 t]     stride 512B, swz ^((h&7)<<4)
//  overlays (phase 2): Q [256 rows][256B] swz ^((row&15)<<4) at [0,65536)
//                      then P: wave w gets [w*8192,+8192), [16][512B] swz ^(lrow<<4)
#define XS0 0
#define XS1 20480
#define WS0 40960
#define WS1 56320
#define KOFF 71680
#define VOFF 104448

__global__ __launch_bounds__(512, 2) void fused_head(
    const float* __restrict__ x, const unsigned short* __restrict__ Wt,
    float* __restrict__ out) {
  __shared__ char smem[137216];
  const int tid = threadIdx.x;
  const int w = tid >> 6;          // wave 0..7
  const int lane = tid & 63;
  const int l15 = lane & 15, g = lane >> 4;
  const int b = blockIdx.x;
  const float* xb = x + (size_t)b * 256 * 768;

  // ---------------- phase 1: QKV projection ----------------
  f32x4 acc[2][12];
  #pragma unroll
  for (int rt = 0; rt < 2; ++rt)
    #pragma unroll
    for (int ct = 0; ct < 12; ++ct) acc[rt][ct] = f32x4{0.f, 0.f, 0.f, 0.f};

  const int sxr = tid >> 3;   // x staging: row within 64-row band
  const int sxc = tid & 7;    // 16B chunk (4 floats)
  const int widx0 = tid;      // Wt staging: chunk ids tid, tid+512 (<768)
  const int widx1 = 512 + tid;

  float4 xreg[4];
  short8 wreg[2];

  auto load_tiles = [&](int kk) {
    #pragma unroll
    for (int p = 0; p < 4; ++p)
      xreg[p] = *reinterpret_cast<const float4*>(
          xb + (size_t)(p * 64 + sxr) * 768 + kk + sxc * 4);
    wreg[0] = *reinterpret_cast<const short8*>(
        Wt + (size_t)(widx0 >> 2) * 768 + kk + (widx0 & 3) * 8);
    if (widx1 < 768)
      wreg[1] = *reinterpret_cast<const short8*>(
          Wt + (size_t)(widx1 >> 2) * 768 + kk + (widx1 & 3) * 8);
  };
  auto store_tiles = [&](char* xsb, char* wsb) {
    #pragma unroll
    for (int p = 0; p < 4; ++p) {
      short4v v;
      v[0] = (short)f2bf(xreg[p].x); v[1] = (short)f2bf(xreg[p].y);
      v[2] = (short)f2bf(xreg[p].z); v[3] = (short)f2bf(xreg[p].w);
      *reinterpret_cast<short4v*>(xsb + (p * 64 + sxr) * 80 + sxc * 8) = v;
    }
    *reinterpret_cast<short8*>(wsb + (widx0 >> 2) * 80 + (widx0 & 3) * 16) = wreg[0];
    if (widx1 < 768)
      *reinterpret_cast<short8*>(wsb + (widx1 >> 2) * 80 + (widx1 & 3) * 16) = wreg[1];
  };

  load_tiles(0);
  store_tiles(smem + XS0, smem + WS0);

  for (int it = 0; it < 24; ++it) {
    __syncthreads();
    const int cur = it & 1;
    if (it < 23) load_tiles((it + 1) * 32);
    char* xsb = smem + (cur ? XS1 : XS0);
    char* wsb = smem + (cur ? WS1 : WS0);
    short8 a0 = *reinterpret_cast<const short8*>(xsb + (w * 32 + l15) * 80 + g * 16);
    short8 a1 = *reinterpret_cast<const short8*>(xsb + (w * 32 + 16 + l15) * 80 + g * 16);
    #pragma unroll
    for (int ct = 0; ct < 12; ++ct) {
      short8 bb = *reinterpret_cast<const short8*>(wsb + (ct * 16 + l15) * 80 + g * 16);
      acc[0][ct] = MFMA16(a0, bb, acc[0][ct]);
      acc[1][ct] = MFMA16(a1, bb, acc[1][ct]);
    }
    if (it < 23) store_tiles(smem + (cur ? XS0 : XS1), smem + (cur ? WS0 : WS1));
  }
  __syncthreads();

  // ---------------- epilogue: accs -> LDS (K, Vt, Q) ----------------
  char* Kl = smem + KOFF;
  char* Vl = smem + VOFF;
  char* Ql = smem;  // overlays staging
  #pragma unroll
  for (int rt = 0; rt < 2; ++rt) {
    #pragma unroll
    for (int ct = 0; ct < 4; ++ct) {
      #pragma unroll
      for (int r = 0; r < 4; ++r) {
        int key = w * 32 + rt * 16 + g * 4 + r;
        int h = ct * 16 + l15;
        *reinterpret_cast<unsigned short*>(
            Kl + key * 128 + ((h * 2) ^ ((key & 7) << 4))) = f2bf(acc[rt][4 + ct][r]);
        *reinterpret_cast<unsigned short*>(
            Ql + key * 256 + ((h * 2) ^ ((key & 15) << 4))) =
            f2bf(0.125f * acc[rt][ct][r]);  // fold 1/sqrt(H) into Q (exact pow2)
      }
      // V: 4 consecutive t -> one b64
      int h = ct * 16 + l15;
      int t0 = w * 32 + rt * 16 + g * 4;
      short4v pv;
      pv[0] = (short)f2bf(acc[rt][8 + ct][0]); pv[1] = (short)f2bf(acc[rt][8 + ct][1]);
      pv[2] = (short)f2bf(acc[rt][8 + ct][2]); pv[3] = (short)f2bf(acc[rt][8 + ct][3]);
      *reinterpret_cast<short4v*>(Vl + h * 512 + ((t0 * 2) ^ ((h & 7) << 4))) = pv;
    }
  }
  __syncthreads();

  // read Q fragments, then free the Q region for P
  short8 qf[2][2];
  #pragma unroll
  for (int rt = 0; rt < 2; ++rt)
    #pragma unroll
    for (int c = 0; c < 2; ++c) {
      int row = w * 32 + rt * 16 + l15;
      qf[rt][c] = *reinterpret_cast<const short8*>(
          Ql + row * 256 + ((c * 64 + g * 16) ^ ((row & 15) << 4)));
    }
  __syncthreads();

  // ---------------- phase 2: causal attention (per wave, 2x16 q-rows) -------
  char* Pw = smem + w * 8192;  // this wave's P: [16 rows][512B], swz ^(lrow<<4)

  #pragma unroll
  for (int rt = 0; rt < 2; ++rt) {
    const int trow0 = w * 32 + rt * 16;
    const int ntile = (trow0 >> 4) + 1;  // causal: key tiles 0..ntile-1
    f32x4 s[16];

    #pragma unroll
    for (int t = 0; t < 16; ++t) {
      if (t < ntile) {
        int key = t * 16 + l15;
        int swz = (l15 & 7) << 4;
        short8 b0 = *reinterpret_cast<const short8*>(Kl + key * 128 + ((g * 16) ^ swz));
        short8 b1 = *reinterpret_cast<const short8*>(Kl + key * 128 + ((64 + g * 16) ^ swz));
        f32x4 a = f32x4{0.f, 0.f, 0.f, 0.f};
        a = MFMA16(qf[rt][0], b0, a);
        a = MFMA16(qf[rt][1], b1, a);
        s[t] = a;
      }
    }

    // mask diagonal tile + row max
    float mx[4] = {-1e30f, -1e30f, -1e30f, -1e30f};
    #pragma unroll
    for (int t = 0; t < 16; ++t) {
      if (t < ntile) {
        if (t == ntile - 1) {
          #pragma unroll
          for (int r = 0; r < 4; ++r)
            if (l15 > g * 4 + r) s[t][r] = -1e30f;
        }
        #pragma unroll
        for (int r = 0; r < 4; ++r) mx[r] = fmaxf(mx[r], s[t][r]);
      }
    }
    #pragma unroll
    for (int r = 0; r < 4; ++r) {
      mx[r] = fmaxf(mx[r], __shfl_xor(mx[r], 1));
      mx[r] = fmaxf(mx[r], __shfl_xor(mx[r], 2));
      mx[r] = fmaxf(mx[r], __shfl_xor(mx[r], 4));
      mx[r] = fmaxf(mx[r], __shfl_xor(mx[r], 8));
    }
    float sm[4] = {0.f, 0.f, 0.f, 0.f};
    #pragma unroll
    for (int t = 0; t < 16; ++t) {
      if (t < ntile) {
        #pragma unroll
        for (int r = 0; r < 4; ++r) {
          float p = __expf(s[t][r] - mx[r]);
          s[t][r] = p;
          sm[r] += p;
        }
      }
    }
    float inv[4];
    #pragma unroll
    for (int r = 0; r < 4; ++r) {
      sm[r] += __shfl_xor(sm[r], 1);
      sm[r] += __shfl_xor(sm[r], 2);
      sm[r] += __shfl_xor(sm[r], 4);
      sm[r] += __shfl_xor(sm[r], 8);
      inv[r] = 1.0f / sm[r];
    }

    // write P (normalized bf16) into wave-private swizzled region
    #pragma unroll
    for (int t = 0; t < 16; ++t) {
      if (t < ntile) {
        #pragma unroll
        for (int r = 0; r < 4; ++r) {
          int lrow = g * 4 + r;
          *reinterpret_cast<unsigned short*>(
              Pw + lrow * 512 + (((t * 16 + l15) * 2) ^ (lrow << 4))) =
              f2bf(s[t][r] * inv[r]);
        }
      }
    }
    if (ntile & 1) {  // zero-pad tile ntile so the last 32-key PV chunk is clean
      #pragma unroll
      for (int r = 0; r < 4; ++r) {
        int lrow = g * 4 + r;
        *reinterpret_cast<unsigned short*>(
            Pw + lrow * 512 + (((ntile * 16 + l15) * 2) ^ (lrow << 4))) = 0;
      }
    }

    // O = P V
    const int nkc = (ntile + 1) >> 1;
    f32x4 o[4];
    #pragma unroll
    for (int i = 0; i < 4; ++i) o[i] = f32x4{0.f, 0.f, 0.f, 0.f};
    #pragma unroll
    for (int kc = 0; kc < 8; ++kc) {
      if (kc < nkc) {
        short8 pa = *reinterpret_cast<const short8*>(
            Pw + l15 * 512 + ((kc * 64 + g * 16) ^ (l15 << 4)));
        #pragma unroll
        for (int ht = 0; ht < 4; ++ht) {
          int h = ht * 16 + l15;
          short8 bv = *reinterpret_cast<const short8*>(
              Vl + h * 512 + ((kc * 64 + g * 16) ^ ((h & 7) << 4)));
          o[ht] = MFMA16(pa, bv, o[ht]);
        }
      }
    }

    // store out fp32 [b][t][h]
    #pragma unroll
    for (int r = 0; r < 4; ++r) {
      int trow = trow0 + g * 4 + r;
      float* dst = out + ((size_t)b * 256 + trow) * 64 + l15;
      #pragma unroll
      for (int ht = 0; ht < 4; ++ht) dst[ht * 16] = o[ht][r];
    }
  }
}

// ---------------------------------------------------------------- launch
extern "C" void kernel_launch(void* const* d_in, const int* in_sizes, int n_in,
                              void* d_out, int out_size, void* d_ws, size_t ws_size,
                              hipStream_t stream) {
  const float* x  = (const float*)d_in[0];
  const float* Wq = (const float*)d_in[1];
  const float* Wk = (const float*)d_in[2];
  const float* Wv = (const float*)d_in[3];
  unsigned short* Wt = (unsigned short*)d_ws;  // 294912 B
  float* out = (float*)d_out;

  hipLaunchKernelGGL(wt_prep, dim3(576), dim3(256), 0, stream, Wq, Wk, Wv, Wt);
  hipLaunchKernelGGL(fused_head, dim3(256), dim3(512), 0, stream, x, Wt, out);
}